// Round 4
// baseline (264.073 us; speedup 1.0000x reference)
//
#include <hip/hip_runtime.h>

// ---------------------------------------------------------------------------
// GCN link prediction forward on MI355X.  R4: edge-list read ONCE -> 8
// per-XCD-partition queues (bucket pass), then XCD-local ELL scatter.
//  0) memset: cnt/qcur = 0
//  1) prep_wfrag: W1 -> bf16 MFMA A-fragment table (32 KB global)
//  2) bucket_edges: queues[p] += (src,dst) for dst in slice p  (1 read of E)
//  3) scatter_ell: colsrc[d][atomicAdd(cnt[d])] = src  (queue p on XCD p;
//     cnt/colsrc lines single-XCD-owned, L2-local atomics)
//  4) dinv_k: dinv[v] = rsqrt(min(cnt,64)+1)
//  5) gemm1_mfma: h1b = bf16((emb[x] @ W1) * dinv)   [N][128] bf16
//  6) agg1_ln: h2b = bf16(LN(relu(dinv*sum h1b + b1)))  (wave/node)
//  7) gemm2: zsb = bf16((h2b @ W2) * dinv)
//  8) agg2: z = dinv*(sum zsb) + b2
//  9) decode: out = ((concat(z[a],z[b]) @ L1 + bl1) @ L2 + bl2)
// ---------------------------------------------------------------------------

typedef __attribute__((ext_vector_type(8))) __bf16 bf16x8;
typedef __attribute__((ext_vector_type(4))) __bf16 bf16x4;
typedef __attribute__((ext_vector_type(4))) float f32x4;

static __device__ __forceinline__ unsigned f2bf1(float x) {
  unsigned u = __float_as_uint(x);
  return (u + 0x7FFFu + ((u >> 16) & 1u)) >> 16;
}
static __device__ __forceinline__ unsigned packbf2(float lo, float hi) {
  return f2bf1(lo) | (f2bf1(hi) << 16);
}
static __device__ __forceinline__ float bfl(unsigned u) { return __uint_as_float(u << 16); }
static __device__ __forceinline__ float bfh(unsigned u) { return __uint_as_float(u & 0xFFFF0000u); }

// W1 fragment table: wfrag[((kt*8+ct)*64+lane)*8+j] = bf16(W1[kt*32+(lane>>4)*8+j][ct*16+(lane&15)])
__global__ __launch_bounds__(256) void prep_wfrag(const float* __restrict__ W1,
                                                  ushort* __restrict__ wfrag) {
  int idx = blockIdx.x * 256 + threadIdx.x;  // 64 blocks -> 16384 elements
  int j = idx & 7, lane = (idx >> 3) & 63, ct = (idx >> 9) & 7, kt = idx >> 12;
  int k = kt * 32 + (lane >> 4) * 8 + j;
  int col = ct * 16 + (lane & 15);
  __bf16 h = (__bf16)W1[k * 128 + col];
  wfrag[idx] = __builtin_bit_cast(ushort, h);
}

// Pass 1: read edges once, route to 8 per-partition queues.
__global__ __launch_bounds__(256) void bucket_edges(const int* __restrict__ src,
                                                    const int* __restrict__ dst,
                                                    int E, float invS,
                                                    int* __restrict__ qcur,
                                                    uint2* __restrict__ queues,
                                                    int qcap) {
  __shared__ int lcnt[8];
  __shared__ int lbase[8];
  int t = threadIdx.x;
  int CH = (E + gridDim.x - 1) / gridDim.x;
  int beg = blockIdx.x * CH;
  int end = min(E, beg + CH);
  if (t < 8) lcnt[t] = 0;
  __syncthreads();
  for (int e = beg + t; e < end; e += 256) {
    int p = min(7, (int)((float)dst[e] * invS));
    atomicAdd(&lcnt[p], 1);
  }
  __syncthreads();
  if (t < 8) {
    lbase[t] = atomicAdd(&qcur[t], lcnt[t]);
    lcnt[t] = 0;
  }
  __syncthreads();
  for (int e = beg + t; e < end; e += 256) {  // chunk is L1/L2-hot now
    int d = dst[e];
    int p = min(7, (int)((float)d * invS));
    int pos = lbase[p] + atomicAdd(&lcnt[p], 1);
    if (pos < qcap) queues[(size_t)p * qcap + pos] = make_uint2((unsigned)src[e], (unsigned)d);
  }
}

// Pass 2: each XCD drains its own queue; cnt/colsrc writes are L2-local.
__global__ __launch_bounds__(256) void scatter_ell(const uint2* __restrict__ queues,
                                                   const int* __restrict__ qcur,
                                                   int qcap, int* __restrict__ cnt,
                                                   int* __restrict__ colsrc) {
  int p = blockIdx.x & 7;
  int b = blockIdx.x >> 3;
  int nb = gridDim.x >> 3;
  int len = min(qcur[p], qcap);
  const uint2* q = queues + (size_t)p * qcap;
  for (int i = b * 256 + threadIdx.x; i < len; i += nb * 256) {
    uint2 e = q[i];
    int pos = atomicAdd(&cnt[e.y], 1);
    if (pos < 64) colsrc[(size_t)e.y * 64 + pos] = (int)e.x;
  }
}

__global__ __launch_bounds__(256) void dinv_k(const int* __restrict__ cnt,
                                              float* __restrict__ dinv, int N) {
  int v = blockIdx.x * 256 + threadIdx.x;
  if (v < N) dinv[v] = rsqrtf((float)(min(cnt[v], 64) + 1));
}

// h1b[node][dim] bf16 = (emb[x[node]] @ W1) * dinv[node], via 16x16x32 MFMA.
__global__ __launch_bounds__(256) void gemm1_mfma(
    const int* __restrict__ x, const float* __restrict__ emb,
    const ushort* __restrict__ wfrag, const float* __restrict__ dinv,
    unsigned* __restrict__ h1b, int N) {
  __shared__ alignas(16) ushort Wlds[16384];  // 32 KB frag table
  int t = threadIdx.x;
  for (int i = t; i < 2048; i += 256)
    ((uint4*)Wlds)[i] = ((const uint4*)wfrag)[i];
  __syncthreads();
  int w = t >> 6, lane = t & 63;
  int row0 = blockIdx.x * 128 + w * 32;  // this wave: nodes row0..row0+31
  int rB = lane & 15, kg = lane >> 4;
  int n0 = row0 + rB, n1 = row0 + 16 + rB;
  const float* e0 = emb + (size_t)x[min(n0, N - 1)] * 128 + kg * 8;
  const float* e1 = emb + (size_t)x[min(n1, N - 1)] * 128 + kg * 8;
  f32x4 acc[2][8];
#pragma unroll
  for (int g = 0; g < 2; ++g)
#pragma unroll
    for (int ct = 0; ct < 8; ++ct) acc[g][ct] = (f32x4)(0.f);
#pragma unroll
  for (int kt = 0; kt < 4; ++kt) {
    float4 p0 = *(const float4*)(e0 + kt * 32);
    float4 p1 = *(const float4*)(e0 + kt * 32 + 4);
    float4 q0 = *(const float4*)(e1 + kt * 32);
    float4 q1 = *(const float4*)(e1 + kt * 32 + 4);
    bf16x8 fb0, fb1;
    fb0[0] = (__bf16)p0.x; fb0[1] = (__bf16)p0.y; fb0[2] = (__bf16)p0.z; fb0[3] = (__bf16)p0.w;
    fb0[4] = (__bf16)p1.x; fb0[5] = (__bf16)p1.y; fb0[6] = (__bf16)p1.z; fb0[7] = (__bf16)p1.w;
    fb1[0] = (__bf16)q0.x; fb1[1] = (__bf16)q0.y; fb1[2] = (__bf16)q0.z; fb1[3] = (__bf16)q0.w;
    fb1[4] = (__bf16)q1.x; fb1[5] = (__bf16)q1.y; fb1[6] = (__bf16)q1.z; fb1[7] = (__bf16)q1.w;
#pragma unroll
    for (int ct = 0; ct < 8; ++ct) {
      bf16x8 wv = *(const bf16x8*)&Wlds[((kt * 8 + ct) * 64 + lane) * 8];
      acc[0][ct] = __builtin_amdgcn_mfma_f32_16x16x32_bf16(wv, fb0, acc[0][ct], 0, 0, 0);
      acc[1][ct] = __builtin_amdgcn_mfma_f32_16x16x32_bf16(wv, fb1, acc[1][ct], 0, 0, 0);
    }
  }
#pragma unroll
  for (int g = 0; g < 2; ++g) {
    int node = row0 + g * 16 + rB;
    if (node < N) {
      float dv = dinv[node];
#pragma unroll
      for (int ct = 0; ct < 8; ++ct) {
        f32x4 a = acc[g][ct];
        bf16x4 o;
        o[0] = (__bf16)(a[0] * dv); o[1] = (__bf16)(a[1] * dv);
        o[2] = (__bf16)(a[2] * dv); o[3] = (__bf16)(a[3] * dv);
        *(uint2*)&h1b[(size_t)node * 64 + ct * 8 + kg * 2] = __builtin_bit_cast(uint2, o);
      }
    }
  }
}

// wave per node: acc = h1b[v] + sum_nbr h1b[s]; h2b = bf16(LN(relu(acc*dinv+b1)))
__global__ __launch_bounds__(256) void agg1_ln(const unsigned* __restrict__ h1b,
                                               const int* __restrict__ cnt_a,
                                               const int* __restrict__ colsrc,
                                               const float* __restrict__ dinv,
                                               const float* __restrict__ b1,
                                               const float* __restrict__ lng,
                                               const float* __restrict__ lnb,
                                               unsigned* __restrict__ h2b, int N) {
  int v = blockIdx.x * 4 + (threadIdx.x >> 6);
  int lane = threadIdx.x & 63;
  if (v >= N) return;
  int myidx = colsrc[(size_t)v * 64 + lane];  // whole ELL row in one wave-load
  int cnt = min(cnt_a[v], 64);
  unsigned ms = h1b[(size_t)v * 64 + lane];  // self loop (pre-scaled)
  float accx = bfl(ms), accy = bfh(ms);
  int i = 0;
  for (; i + 4 <= cnt; i += 4) {  // 4 gathers in flight, indices via shfl
    int s0 = __shfl(myidx, i, 64), s1 = __shfl(myidx, i + 1, 64);
    int s2 = __shfl(myidx, i + 2, 64), s3 = __shfl(myidx, i + 3, 64);
    unsigned m0 = h1b[(size_t)s0 * 64 + lane];
    unsigned m1 = h1b[(size_t)s1 * 64 + lane];
    unsigned m2 = h1b[(size_t)s2 * 64 + lane];
    unsigned m3 = h1b[(size_t)s3 * 64 + lane];
    accx += (bfl(m0) + bfl(m1)) + (bfl(m2) + bfl(m3));
    accy += (bfh(m0) + bfh(m1)) + (bfh(m2) + bfh(m3));
  }
  for (; i < cnt; ++i) {
    unsigned m = h1b[(size_t)__shfl(myidx, i, 64) * 64 + lane];
    accx += bfl(m);
    accy += bfh(m);
  }
  float dv = dinv[v];
  float2 bb = ((const float2*)b1)[lane];
  float vx = fmaxf(accx * dv + bb.x, 0.f);
  float vy = fmaxf(accy * dv + bb.y, 0.f);
  float s1 = vx + vy, s2 = vx * vx + vy * vy;
#pragma unroll
  for (int off = 32; off; off >>= 1) {
    s1 += __shfl_xor(s1, off, 64);
    s2 += __shfl_xor(s2, off, 64);
  }
  float mu = s1 * (1.f / 128.f);
  float var = s2 * (1.f / 128.f) - mu * mu;
  float rs = rsqrtf(var + 1e-5f);
  float2 gg = ((const float2*)lng)[lane];
  float2 nb = ((const float2*)lnb)[lane];
  h2b[(size_t)v * 64 + lane] =
      packbf2((vx - mu) * rs * gg.x + nb.x, (vy - mu) * rs * gg.y + nb.y);
}

// zsb[row][:] = bf16((h2b[row] @ W2) * dinv[row])   (128x16, bf16 input)
__global__ __launch_bounds__(256) void gemm2(const unsigned* __restrict__ h2b,
                                             const float* __restrict__ W2,
                                             const float* __restrict__ dinv,
                                             unsigned* __restrict__ zsb, int N) {
  __shared__ float W2s[128 * 16];  // 8 KB
  int t = threadIdx.x;
#pragma unroll
  for (int i = 0; i < 8; ++i) W2s[t + i * 256] = W2[t + i * 256];
  __syncthreads();
  int cp = t & 7, r = t >> 3;  // cp -> output dims 2cp,2cp+1; 32 rows/tile
  for (int rb = blockIdx.x * 32; rb < N; rb += gridDim.x * 32) {
    int row = rb + r;
    if (row >= N) continue;
    const uint4* xr = (const uint4*)(h2b + (size_t)row * 64);
    float a0 = 0.f, a1 = 0.f;
#pragma unroll
    for (int k8 = 0; k8 < 16; ++k8) {
      uint4 u = xr[k8];
      float f0 = bfl(u.x), f1 = bfh(u.x), f2 = bfl(u.y), f3 = bfh(u.y);
      float f4 = bfl(u.z), f5 = bfh(u.z), f6 = bfl(u.w), f7 = bfh(u.w);
      int kb = k8 * 8;
      float2 w;
      w = ((const float2*)W2s)[(kb + 0) * 8 + cp]; a0 += f0 * w.x; a1 += f0 * w.y;
      w = ((const float2*)W2s)[(kb + 1) * 8 + cp]; a0 += f1 * w.x; a1 += f1 * w.y;
      w = ((const float2*)W2s)[(kb + 2) * 8 + cp]; a0 += f2 * w.x; a1 += f2 * w.y;
      w = ((const float2*)W2s)[(kb + 3) * 8 + cp]; a0 += f3 * w.x; a1 += f3 * w.y;
      w = ((const float2*)W2s)[(kb + 4) * 8 + cp]; a0 += f4 * w.x; a1 += f4 * w.y;
      w = ((const float2*)W2s)[(kb + 5) * 8 + cp]; a0 += f5 * w.x; a1 += f5 * w.y;
      w = ((const float2*)W2s)[(kb + 6) * 8 + cp]; a0 += f6 * w.x; a1 += f6 * w.y;
      w = ((const float2*)W2s)[(kb + 7) * 8 + cp]; a0 += f7 * w.x; a1 += f7 * w.y;
    }
    float dv = dinv[row];
    zsb[(size_t)row * 8 + cp] = packbf2(a0 * dv, a1 * dv);
  }
}

// wave per node: 8 neighbor groups x (8 lanes x 2 dims), shfl-xor reduce.
__global__ __launch_bounds__(256) void agg2(const unsigned* __restrict__ zsb,
                                            const int* __restrict__ cnt_a,
                                            const int* __restrict__ colsrc,
                                            const float* __restrict__ dinv,
                                            const float* __restrict__ b2,
                                            float* __restrict__ z, int N) {
  int v = blockIdx.x * 4 + (threadIdx.x >> 6);
  int lane = threadIdx.x & 63;
  int g = lane >> 3, h = lane & 7;
  if (v >= N) return;
  float ax = 0.f, ay = 0.f;
  if (g == 0) {
    unsigned m = zsb[(size_t)v * 8 + h];
    ax = bfl(m); ay = bfh(m);
  }
  int cnt = min(cnt_a[v], 64);
  const int* cs = colsrc + (size_t)v * 64;
  for (int i = g; i < cnt; i += 8) {
    unsigned m = zsb[(size_t)cs[i] * 8 + h];
    ax += bfl(m); ay += bfh(m);
  }
#pragma unroll
  for (int off = 8; off < 64; off <<= 1) {
    ax += __shfl_xor(ax, off, 64);
    ay += __shfl_xor(ay, off, 64);
  }
  if (g == 0) {
    float dv = dinv[v];
    float2 bb = ((const float2*)b2)[h];
    float2 o;
    o.x = ax * dv + bb.x;
    o.y = ay * dv + bb.y;
    ((float2*)z)[(size_t)v * 8 + h] = o;
  }
}

__global__ __launch_bounds__(256) void decode(const int* __restrict__ eli,
                                              const float* __restrict__ z,
                                              const float* __restrict__ L1,
                                              const float* __restrict__ bl1,
                                              const float* __restrict__ L2,
                                              const float* __restrict__ bl2,
                                              float* __restrict__ out, int EL) {
  __shared__ float L1s[32 * 16];
  __shared__ float L2s[16];
  __shared__ float bl1s[16];
  __shared__ float bl2s;
  int t = threadIdx.x;
  L1s[t] = L1[t];
  L1s[256 + t] = L1[256 + t];
  if (t < 16) { L2s[t] = L2[t]; bl1s[t] = bl1[t]; }
  if (t == 0) bl2s = bl2[0];
  __syncthreads();
  int l = blockIdx.x * 256 + t;
  if (l >= EL) return;
  int a = eli[l], b = eli[EL + l];
  const float4* za = (const float4*)(z + (size_t)a * 16);
  const float4* zb = (const float4*)(z + (size_t)b * 16);
  float h[16];
#pragma unroll
  for (int j = 0; j < 16; ++j) h[j] = bl1s[j];
#pragma unroll
  for (int k4 = 0; k4 < 4; ++k4) {
    float4 va = za[k4];
    float4 vb = zb[k4];
#pragma unroll
    for (int j = 0; j < 16; ++j) {
      h[j] += va.x * L1s[(k4 * 4 + 0) * 16 + j];
      h[j] += va.y * L1s[(k4 * 4 + 1) * 16 + j];
      h[j] += va.z * L1s[(k4 * 4 + 2) * 16 + j];
      h[j] += va.w * L1s[(k4 * 4 + 3) * 16 + j];
      h[j] += vb.x * L1s[(16 + k4 * 4 + 0) * 16 + j];
      h[j] += vb.y * L1s[(16 + k4 * 4 + 1) * 16 + j];
      h[j] += vb.z * L1s[(16 + k4 * 4 + 2) * 16 + j];
      h[j] += vb.w * L1s[(16 + k4 * 4 + 3) * 16 + j];
    }
  }
  float o = bl2s;
#pragma unroll
  for (int j = 0; j < 16; ++j) o += h[j] * L2s[j];
  out[l] = o;
}

extern "C" void kernel_launch(void* const* d_in, const int* in_sizes, int n_in,
                              void* d_out, int out_size, void* d_ws, size_t ws_size,
                              hipStream_t stream) {
  const int* x = (const int*)d_in[0];
  const int* ei = (const int*)d_in[1];
  const int* eli = (const int*)d_in[2];
  const float* emb = (const float*)d_in[3];
  const float* W1 = (const float*)d_in[4];
  const float* b1 = (const float*)d_in[5];
  const float* lng = (const float*)d_in[6];
  const float* lnb = (const float*)d_in[7];
  const float* W2 = (const float*)d_in[8];
  const float* b2 = (const float*)d_in[9];
  const float* L1 = (const float*)d_in[10];
  const float* bl1 = (const float*)d_in[11];
  const float* L2 = (const float*)d_in[12];
  const float* bl2 = (const float*)d_in[13];

  int N = in_sizes[0];
  int E = in_sizes[1] / 2;
  int EL = in_sizes[2] / 2;
  const int* src = ei;
  const int* dst = ei + E;

  char* ws = (char*)d_ws;
  auto align256 = [](size_t v) { return (v + 255) & ~(size_t)255; };
  size_t p = 0;
  int* cnt = (int*)(ws + p); p += align256((size_t)N * 4);
  int* qcur = (int*)(ws + p); p += 256;
  size_t zero_bytes = p;  // cnt + qcur contiguous from 0
  float* dinv = (float*)(ws + p); p += align256((size_t)N * 4);
  ushort* wfrag = (ushort*)(ws + p); p += align256(16384 * 2);
  int* colsrc = (int*)(ws + p); p += align256((size_t)N * 64 * 4);
  int qcap = E / 8 + 8192;
  uint2* queues = (uint2*)(ws + p); p += align256((size_t)8 * qcap * 8);
  unsigned* h1b = (unsigned*)(ws + p); p += align256((size_t)N * 64 * 4);
  unsigned* h2b = (unsigned*)(ws + p); p += align256((size_t)N * 64 * 4);
  unsigned* zsb = (unsigned*)(ws + p); p += align256((size_t)N * 8 * 4);
  float* z = (float*)(ws + p); p += align256((size_t)N * 16 * 4);
  (void)ws_size; (void)n_in; (void)out_size;

  hipMemsetAsync(ws, 0, zero_bytes, stream);

  float invS = 1.0f / (float)((N + 7) / 8);
  prep_wfrag<<<64, 256, 0, stream>>>(W1, wfrag);
  bucket_edges<<<1024, 256, 0, stream>>>(src, dst, E, invS, qcur, queues, qcap);
  scatter_ell<<<2048, 256, 0, stream>>>(queues, qcur, qcap, cnt, colsrc);
  dinv_k<<<(N + 255) / 256, 256, 0, stream>>>(cnt, dinv, N);
  gemm1_mfma<<<(N + 127) / 128, 256, 0, stream>>>(x, emb, wfrag, dinv, h1b, N);
  agg1_ln<<<(N + 3) / 4, 256, 0, stream>>>(h1b, cnt, colsrc, dinv, b1, lng, lnb, h2b, N);
  gemm2<<<512, 256, 0, stream>>>(h2b, W2, dinv, zsb, N);
  agg2<<<(N + 3) / 4, 256, 0, stream>>>(zsb, cnt, colsrc, dinv, b2, z, N);
  decode<<<(EL + 255) / 256, 256, 0, stream>>>(eli, z, L1, bl1, L2, bl2,
                                               (float*)d_out, EL);
}

// Round 5
// 212.647 us; speedup vs baseline: 1.2418x; 1.2418x over previous
//
#include <hip/hip_runtime.h>

// ---------------------------------------------------------------------------
// GCN link prediction forward on MI355X.  R5: power-of-2 dst-slice buckets
// (1024 nodes each) + LDS-atomic ELL scatter; 8B/lane gather restructure in
// both aggregation kernels (2 neighbors per wave step in agg1, 16 in agg2).
//  0) memset: qcur = 0 (4 KB)
//  1) prep_wfrag: W1 -> bf16 MFMA A-fragment table (32 KB global)
//  2) bucket_edges: queues[d>>10] += (src,dst)   (1 read of edge list)
//  3) scatter_ell: block b owns nodes [b*1024,(b+1)*1024); cnt slice in LDS,
//     per-edge position via LDS atomic; writes cnt wholesale (no pre-zero)
//  4) dinv_k: dinv[v] = rsqrt(cnt+1)
//  5) gemm1_mfma: h1b = bf16((emb[x] @ W1) * dinv)   [N][128] bf16
//  6) agg1_ln: h2b = bf16(LN(relu(dinv*sum h1b + b1)))  (wave/node, 8B/lane)
//  7) gemm2: zsb = bf16((h2b @ W2) * dinv)
//  8) agg2: z = dinv*(sum zsb) + b2                (wave/node, 8B/lane)
//  9) decode: out = ((concat(z[a],z[b]) @ L1 + bl1) @ L2 + bl2)
// ---------------------------------------------------------------------------

typedef __attribute__((ext_vector_type(8))) __bf16 bf16x8;
typedef __attribute__((ext_vector_type(4))) __bf16 bf16x4;
typedef __attribute__((ext_vector_type(4))) float f32x4;

static __device__ __forceinline__ unsigned f2bf1(float x) {
  unsigned u = __float_as_uint(x);
  return (u + 0x7FFFu + ((u >> 16) & 1u)) >> 16;
}
static __device__ __forceinline__ unsigned packbf2(float lo, float hi) {
  return f2bf1(lo) | (f2bf1(hi) << 16);
}
static __device__ __forceinline__ float bfl(unsigned u) { return __uint_as_float(u << 16); }
static __device__ __forceinline__ float bfh(unsigned u) { return __uint_as_float(u & 0xFFFF0000u); }

// W1 fragment table: wfrag[((kt*8+ct)*64+lane)*8+j] = bf16(W1[kt*32+(lane>>4)*8+j][ct*16+(lane&15)])
__global__ __launch_bounds__(256) void prep_wfrag(const float* __restrict__ W1,
                                                  ushort* __restrict__ wfrag) {
  int idx = blockIdx.x * 256 + threadIdx.x;  // 64 blocks -> 16384 elements
  int j = idx & 7, lane = (idx >> 3) & 63, ct = (idx >> 9) & 7, kt = idx >> 12;
  int k = kt * 32 + (lane >> 4) * 8 + j;
  int col = ct * 16 + (lane & 15);
  __bf16 h = (__bf16)W1[k * 128 + col];
  wfrag[idx] = __builtin_bit_cast(ushort, h);
}

// Pass 1: read edges once, route to NB per-slice queues (slice = 1024 dsts).
__global__ __launch_bounds__(256) void bucket_edges(const int* __restrict__ src,
                                                    const int* __restrict__ dst,
                                                    int E, int NB,
                                                    int* __restrict__ qcur,
                                                    uint2* __restrict__ queues,
                                                    int qcap) {
  __shared__ int lcnt[128];
  __shared__ int lbase[128];
  int t = threadIdx.x;
  int CH = (E + gridDim.x - 1) / gridDim.x;
  int beg = blockIdx.x * CH;
  int end = min(E, beg + CH);
  for (int i = t; i < NB; i += 256) lcnt[i] = 0;
  __syncthreads();
  for (int e = beg + t; e < end; e += 256) atomicAdd(&lcnt[dst[e] >> 10], 1);
  __syncthreads();
  for (int i = t; i < NB; i += 256) {
    lbase[i] = atomicAdd(&qcur[i], lcnt[i]);
    lcnt[i] = 0;
  }
  __syncthreads();
  for (int e = beg + t; e < end; e += 256) {  // chunk is L2-hot now
    int d = dst[e];
    int p = d >> 10;
    int pos = lbase[p] + atomicAdd(&lcnt[p], 1);
    if (pos < qcap) queues[(size_t)p * qcap + pos] = make_uint2((unsigned)src[e], (unsigned)d);
  }
}

// Pass 2: one block per slice; cnt slice lives in LDS (fast atomics).
__global__ __launch_bounds__(1024) void scatter_ell(const uint2* __restrict__ queues,
                                                    const int* __restrict__ qcur,
                                                    int qcap, int* __restrict__ cnt,
                                                    int* __restrict__ colsrc, int N) {
  __shared__ int lcnt[1024];
  int b = blockIdx.x, t = threadIdx.x;
  lcnt[t] = 0;
  __syncthreads();
  int len = min(qcur[b], qcap);
  const uint2* q = queues + (size_t)b * qcap;
  int lo = b << 10;
  for (int i = t; i < len; i += 1024) {
    uint2 e = q[i];
    int pos = atomicAdd(&lcnt[e.y - lo], 1);
    if (pos < 64) colsrc[(size_t)e.y * 64 + pos] = (int)e.x;
  }
  __syncthreads();
  int node = lo + t;
  if (node < N) cnt[node] = lcnt[t];
}

__global__ __launch_bounds__(256) void dinv_k(const int* __restrict__ cnt,
                                              float* __restrict__ dinv, int N) {
  int v = blockIdx.x * 256 + threadIdx.x;
  if (v < N) dinv[v] = rsqrtf((float)(cnt[v] + 1));
}

// h1b[node][dim] bf16 = (emb[x[node]] @ W1) * dinv[node], via 16x16x32 MFMA.
__global__ __launch_bounds__(256) void gemm1_mfma(
    const int* __restrict__ x, const float* __restrict__ emb,
    const ushort* __restrict__ wfrag, const float* __restrict__ dinv,
    unsigned* __restrict__ h1b, int N) {
  __shared__ alignas(16) ushort Wlds[16384];  // 32 KB frag table
  int t = threadIdx.x;
  for (int i = t; i < 2048; i += 256)
    ((uint4*)Wlds)[i] = ((const uint4*)wfrag)[i];
  __syncthreads();
  int w = t >> 6, lane = t & 63;
  int row0 = blockIdx.x * 128 + w * 32;  // this wave: nodes row0..row0+31
  int rB = lane & 15, kg = lane >> 4;
  int n0 = row0 + rB, n1 = row0 + 16 + rB;
  const float* e0 = emb + (size_t)x[min(n0, N - 1)] * 128 + kg * 8;
  const float* e1 = emb + (size_t)x[min(n1, N - 1)] * 128 + kg * 8;
  f32x4 acc[2][8];
#pragma unroll
  for (int g = 0; g < 2; ++g)
#pragma unroll
    for (int ct = 0; ct < 8; ++ct) acc[g][ct] = (f32x4)(0.f);
#pragma unroll
  for (int kt = 0; kt < 4; ++kt) {
    float4 p0 = *(const float4*)(e0 + kt * 32);
    float4 p1 = *(const float4*)(e0 + kt * 32 + 4);
    float4 q0 = *(const float4*)(e1 + kt * 32);
    float4 q1 = *(const float4*)(e1 + kt * 32 + 4);
    bf16x8 fb0, fb1;
    fb0[0] = (__bf16)p0.x; fb0[1] = (__bf16)p0.y; fb0[2] = (__bf16)p0.z; fb0[3] = (__bf16)p0.w;
    fb0[4] = (__bf16)p1.x; fb0[5] = (__bf16)p1.y; fb0[6] = (__bf16)p1.z; fb0[7] = (__bf16)p1.w;
    fb1[0] = (__bf16)q0.x; fb1[1] = (__bf16)q0.y; fb1[2] = (__bf16)q0.z; fb1[3] = (__bf16)q0.w;
    fb1[4] = (__bf16)q1.x; fb1[5] = (__bf16)q1.y; fb1[6] = (__bf16)q1.z; fb1[7] = (__bf16)q1.w;
#pragma unroll
    for (int ct = 0; ct < 8; ++ct) {
      bf16x8 wv = *(const bf16x8*)&Wlds[((kt * 8 + ct) * 64 + lane) * 8];
      acc[0][ct] = __builtin_amdgcn_mfma_f32_16x16x32_bf16(wv, fb0, acc[0][ct], 0, 0, 0);
      acc[1][ct] = __builtin_amdgcn_mfma_f32_16x16x32_bf16(wv, fb1, acc[1][ct], 0, 0, 0);
    }
  }
#pragma unroll
  for (int g = 0; g < 2; ++g) {
    int node = row0 + g * 16 + rB;
    if (node < N) {
      float dv = dinv[node];
#pragma unroll
      for (int ct = 0; ct < 8; ++ct) {
        f32x4 a = acc[g][ct];
        bf16x4 o;
        o[0] = (__bf16)(a[0] * dv); o[1] = (__bf16)(a[1] * dv);
        o[2] = (__bf16)(a[2] * dv); o[3] = (__bf16)(a[3] * dv);
        *(uint2*)&h1b[(size_t)node * 64 + ct * 8 + kg * 2] = __builtin_bit_cast(uint2, o);
      }
    }
  }
}

// wave/node: lane=(half,dg); 8B/lane, 2 neighbors per step, unroll 4.
// h2b = bf16(LN(relu(acc*dinv+b1)))
__global__ __launch_bounds__(256) void agg1_ln(const unsigned* __restrict__ h1b,
                                               const int* __restrict__ cnt_a,
                                               const int* __restrict__ colsrc,
                                               const float* __restrict__ dinv,
                                               const float* __restrict__ b1,
                                               const float* __restrict__ lng,
                                               const float* __restrict__ lnb,
                                               unsigned* __restrict__ h2b, int N) {
  int v = blockIdx.x * 4 + (threadIdx.x >> 6);
  int lane = threadIdx.x & 63;
  if (v >= N) return;
  int half = lane >> 5, dg = lane & 31;  // dims 4dg..4dg+3
  const uint2* tb = (const uint2*)h1b;   // row = 32 x uint2
  int myidx = colsrc[(size_t)v * 64 + lane];
  int cnt = min(cnt_a[v], 64);
  float a0 = 0.f, a1 = 0.f, a2 = 0.f, a3 = 0.f;
  if (half == 0) {  // self loop (pre-scaled)
    uint2 ms = tb[(size_t)v * 32 + dg];
    a0 = bfl(ms.x); a1 = bfh(ms.x); a2 = bfl(ms.y); a3 = bfh(ms.y);
  }
  int i = 0;
  for (; i + 8 <= cnt; i += 8) {  // 8 gathers in flight across the wave
    int s0 = __shfl(myidx, i + half, 64);
    int s1 = __shfl(myidx, i + 2 + half, 64);
    int s2 = __shfl(myidx, i + 4 + half, 64);
    int s3 = __shfl(myidx, i + 6 + half, 64);
    uint2 m0 = tb[(size_t)s0 * 32 + dg];
    uint2 m1 = tb[(size_t)s1 * 32 + dg];
    uint2 m2 = tb[(size_t)s2 * 32 + dg];
    uint2 m3 = tb[(size_t)s3 * 32 + dg];
    a0 += (bfl(m0.x) + bfl(m1.x)) + (bfl(m2.x) + bfl(m3.x));
    a1 += (bfh(m0.x) + bfh(m1.x)) + (bfh(m2.x) + bfh(m3.x));
    a2 += (bfl(m0.y) + bfl(m1.y)) + (bfl(m2.y) + bfl(m3.y));
    a3 += (bfh(m0.y) + bfh(m1.y)) + (bfh(m2.y) + bfh(m3.y));
  }
  for (; i < cnt; i += 2) {
    int slot = i + half;
    int s = __shfl(myidx, min(slot, cnt - 1), 64);  // uniform trip; shfl before guard
    uint2 m = tb[(size_t)s * 32 + dg];
    if (slot < cnt) {
      a0 += bfl(m.x); a1 += bfh(m.x); a2 += bfl(m.y); a3 += bfh(m.y);
    }
  }
  a0 += __shfl_xor(a0, 32, 64);
  a1 += __shfl_xor(a1, 32, 64);
  a2 += __shfl_xor(a2, 32, 64);
  a3 += __shfl_xor(a3, 32, 64);
  float dv = dinv[v];
  float4 bb = ((const float4*)b1)[dg];
  float v0 = fmaxf(a0 * dv + bb.x, 0.f);
  float v1 = fmaxf(a1 * dv + bb.y, 0.f);
  float v2 = fmaxf(a2 * dv + bb.z, 0.f);
  float v3 = fmaxf(a3 * dv + bb.w, 0.f);
  float s1 = (v0 + v1) + (v2 + v3);
  float s2 = (v0 * v0 + v1 * v1) + (v2 * v2 + v3 * v3);
#pragma unroll
  for (int off = 16; off; off >>= 1) {
    s1 += __shfl_xor(s1, off, 64);
    s2 += __shfl_xor(s2, off, 64);
  }
  float mu = s1 * (1.f / 128.f);
  float var = s2 * (1.f / 128.f) - mu * mu;
  float rs = rsqrtf(var + 1e-5f);
  float4 gg = ((const float4*)lng)[dg];
  float4 nb = ((const float4*)lnb)[dg];
  if (half == 0) {
    uint2 o;
    o.x = packbf2((v0 - mu) * rs * gg.x + nb.x, (v1 - mu) * rs * gg.y + nb.y);
    o.y = packbf2((v2 - mu) * rs * gg.z + nb.z, (v3 - mu) * rs * gg.w + nb.w);
    ((uint2*)h2b)[(size_t)v * 32 + dg] = o;
  }
}

// zsb[row][:] = bf16((h2b[row] @ W2) * dinv[row])   (128x16, bf16 input)
__global__ __launch_bounds__(256) void gemm2(const unsigned* __restrict__ h2b,
                                             const float* __restrict__ W2,
                                             const float* __restrict__ dinv,
                                             unsigned* __restrict__ zsb, int N) {
  __shared__ float W2s[128 * 16];  // 8 KB
  int t = threadIdx.x;
#pragma unroll
  for (int i = 0; i < 8; ++i) W2s[t + i * 256] = W2[t + i * 256];
  __syncthreads();
  int cp = t & 7, r = t >> 3;  // cp -> output dims 2cp,2cp+1; 32 rows/tile
  for (int rb = blockIdx.x * 32; rb < N; rb += gridDim.x * 32) {
    int row = rb + r;
    if (row >= N) continue;
    const uint4* xr = (const uint4*)(h2b + (size_t)row * 64);
    float a0 = 0.f, a1 = 0.f;
#pragma unroll
    for (int k8 = 0; k8 < 16; ++k8) {
      uint4 u = xr[k8];
      float f0 = bfl(u.x), f1 = bfh(u.x), f2 = bfl(u.y), f3 = bfh(u.y);
      float f4 = bfl(u.z), f5 = bfh(u.z), f6 = bfl(u.w), f7 = bfh(u.w);
      int kb = k8 * 8;
      float2 w;
      w = ((const float2*)W2s)[(kb + 0) * 8 + cp]; a0 += f0 * w.x; a1 += f0 * w.y;
      w = ((const float2*)W2s)[(kb + 1) * 8 + cp]; a0 += f1 * w.x; a1 += f1 * w.y;
      w = ((const float2*)W2s)[(kb + 2) * 8 + cp]; a0 += f2 * w.x; a1 += f2 * w.y;
      w = ((const float2*)W2s)[(kb + 3) * 8 + cp]; a0 += f3 * w.x; a1 += f3 * w.y;
      w = ((const float2*)W2s)[(kb + 4) * 8 + cp]; a0 += f4 * w.x; a1 += f4 * w.y;
      w = ((const float2*)W2s)[(kb + 5) * 8 + cp]; a0 += f5 * w.x; a1 += f5 * w.y;
      w = ((const float2*)W2s)[(kb + 6) * 8 + cp]; a0 += f6 * w.x; a1 += f6 * w.y;
      w = ((const float2*)W2s)[(kb + 7) * 8 + cp]; a0 += f7 * w.x; a1 += f7 * w.y;
    }
    float dv = dinv[row];
    zsb[(size_t)row * 8 + cp] = packbf2(a0 * dv, a1 * dv);
  }
}

// wave/node: lane=(g,q); 4 lanes x 8B per row, 16 neighbors in flight.
__global__ __launch_bounds__(256) void agg2(const unsigned* __restrict__ zsb,
                                            const int* __restrict__ cnt_a,
                                            const int* __restrict__ colsrc,
                                            const float* __restrict__ dinv,
                                            const float* __restrict__ b2,
                                            float* __restrict__ z, int N) {
  int v = blockIdx.x * 4 + (threadIdx.x >> 6);
  int lane = threadIdx.x & 63;
  if (v >= N) return;
  int g = lane >> 2, q = lane & 3;  // 16 neighbor groups, dims 4q..4q+3
  const uint2* tb = (const uint2*)zsb;  // row = 4 x uint2
  int myidx = colsrc[(size_t)v * 64 + lane];
  int cnt = min(cnt_a[v], 64);
  float a0 = 0.f, a1 = 0.f, a2 = 0.f, a3 = 0.f;
  if (g == 0) {  // self loop
    uint2 m = tb[(size_t)v * 4 + q];
    a0 = bfl(m.x); a1 = bfh(m.x); a2 = bfl(m.y); a3 = bfh(m.y);
  }
  for (int i = 0; i < cnt; i += 16) {
    int slot = i + g;
    int s = __shfl(myidx, min(slot, cnt - 1), 64);
    uint2 m = tb[(size_t)s * 4 + q];
    if (slot < cnt) {
      a0 += bfl(m.x); a1 += bfh(m.x); a2 += bfl(m.y); a3 += bfh(m.y);
    }
  }
#pragma unroll
  for (int off = 4; off < 64; off <<= 1) {
    a0 += __shfl_xor(a0, off, 64);
    a1 += __shfl_xor(a1, off, 64);
    a2 += __shfl_xor(a2, off, 64);
    a3 += __shfl_xor(a3, off, 64);
  }
  if (g == 0) {
    float dv = dinv[v];
    float4 bb = ((const float4*)b2)[q];
    float4 o;
    o.x = a0 * dv + bb.x;
    o.y = a1 * dv + bb.y;
    o.z = a2 * dv + bb.z;
    o.w = a3 * dv + bb.w;
    ((float4*)z)[(size_t)v * 4 + q] = o;
  }
}

__global__ __launch_bounds__(256) void decode(const int* __restrict__ eli,
                                              const float* __restrict__ z,
                                              const float* __restrict__ L1,
                                              const float* __restrict__ bl1,
                                              const float* __restrict__ L2,
                                              const float* __restrict__ bl2,
                                              float* __restrict__ out, int EL) {
  __shared__ float L1s[32 * 16];
  __shared__ float L2s[16];
  __shared__ float bl1s[16];
  __shared__ float bl2s;
  int t = threadIdx.x;
  L1s[t] = L1[t];
  L1s[256 + t] = L1[256 + t];
  if (t < 16) { L2s[t] = L2[t]; bl1s[t] = bl1[t]; }
  if (t == 0) bl2s = bl2[0];
  __syncthreads();
  int l = blockIdx.x * 256 + t;
  if (l >= EL) return;
  int a = eli[l], b = eli[EL + l];
  const float4* za = (const float4*)(z + (size_t)a * 16);
  const float4* zb = (const float4*)(z + (size_t)b * 16);
  float h[16];
#pragma unroll
  for (int j = 0; j < 16; ++j) h[j] = bl1s[j];
#pragma unroll
  for (int k4 = 0; k4 < 4; ++k4) {
    float4 va = za[k4];
    float4 vb = zb[k4];
#pragma unroll
    for (int j = 0; j < 16; ++j) {
      h[j] += va.x * L1s[(k4 * 4 + 0) * 16 + j];
      h[j] += va.y * L1s[(k4 * 4 + 1) * 16 + j];
      h[j] += va.z * L1s[(k4 * 4 + 2) * 16 + j];
      h[j] += va.w * L1s[(k4 * 4 + 3) * 16 + j];
      h[j] += vb.x * L1s[(16 + k4 * 4 + 0) * 16 + j];
      h[j] += vb.y * L1s[(16 + k4 * 4 + 1) * 16 + j];
      h[j] += vb.z * L1s[(16 + k4 * 4 + 2) * 16 + j];
      h[j] += vb.w * L1s[(16 + k4 * 4 + 3) * 16 + j];
    }
  }
  float o = bl2s;
#pragma unroll
  for (int j = 0; j < 16; ++j) o += h[j] * L2s[j];
  out[l] = o;
}

extern "C" void kernel_launch(void* const* d_in, const int* in_sizes, int n_in,
                              void* d_out, int out_size, void* d_ws, size_t ws_size,
                              hipStream_t stream) {
  const int* x = (const int*)d_in[0];
  const int* ei = (const int*)d_in[1];
  const int* eli = (const int*)d_in[2];
  const float* emb = (const float*)d_in[3];
  const float* W1 = (const float*)d_in[4];
  const float* b1 = (const float*)d_in[5];
  const float* lng = (const float*)d_in[6];
  const float* lnb = (const float*)d_in[7];
  const float* W2 = (const float*)d_in[8];
  const float* b2 = (const float*)d_in[9];
  const float* L1 = (const float*)d_in[10];
  const float* bl1 = (const float*)d_in[11];
  const float* L2 = (const float*)d_in[12];
  const float* bl2 = (const float*)d_in[13];

  int N = in_sizes[0];
  int E = in_sizes[1] / 2;
  int EL = in_sizes[2] / 2;
  const int* src = ei;
  const int* dst = ei + E;

  int NB = (N + 1023) >> 10;            // 1024-node dst slices
  int qcap = E / NB + 4096;             // Poisson slack

  char* ws = (char*)d_ws;
  auto align256 = [](size_t v) { return (v + 255) & ~(size_t)255; };
  size_t p = 0;
  int* qcur = (int*)(ws + p); p += 4096;  // zeroed (covers NB <= 1024)
  int* cnt = (int*)(ws + p); p += align256((size_t)N * 4);
  float* dinv = (float*)(ws + p); p += align256((size_t)N * 4);
  ushort* wfrag = (ushort*)(ws + p); p += align256(16384 * 2);
  int* colsrc = (int*)(ws + p); p += align256((size_t)N * 64 * 4);
  uint2* queues = (uint2*)(ws + p); p += align256((size_t)NB * qcap * 8);
  unsigned* h1b = (unsigned*)(ws + p); p += align256((size_t)N * 64 * 4);
  unsigned* h2b = (unsigned*)(ws + p); p += align256((size_t)N * 64 * 4);
  unsigned* zsb = (unsigned*)(ws + p); p += align256((size_t)N * 8 * 4);
  float* z = (float*)(ws + p); p += align256((size_t)N * 16 * 4);
  (void)ws_size; (void)n_in; (void)out_size;

  hipMemsetAsync(qcur, 0, 4096, stream);

  prep_wfrag<<<64, 256, 0, stream>>>(W1, wfrag);
  bucket_edges<<<512, 256, 0, stream>>>(src, dst, E, NB, qcur, queues, qcap);
  scatter_ell<<<NB, 1024, 0, stream>>>(queues, qcur, qcap, cnt, colsrc, N);
  dinv_k<<<(N + 255) / 256, 256, 0, stream>>>(cnt, dinv, N);
  gemm1_mfma<<<(N + 127) / 128, 256, 0, stream>>>(x, emb, wfrag, dinv, h1b, N);
  agg1_ln<<<(N + 3) / 4, 256, 0, stream>>>(h1b, cnt, colsrc, dinv, b1, lng, lnb, h2b, N);
  gemm2<<<512, 256, 0, stream>>>(h2b, W2, dinv, zsb, N);
  agg2<<<(N + 3) / 4, 256, 0, stream>>>(zsb, cnt, colsrc, dinv, b2, z, N);
  decode<<<(EL + 255) / 256, 256, 0, stream>>>(eli, z, L1, bl1, L2, bl2,
                                               (float*)d_out, EL);
}

// Round 6
// 202.891 us; speedup vs baseline: 1.3015x; 1.0481x over previous
//
#include <hip/hip_runtime.h>

// ---------------------------------------------------------------------------
// GCN link prediction forward on MI355X.  R6: agg1 gathers uint4 (16B/lane,
// 4 neighbor-groups x 16 lanes, 8 rows in flight, ~5 wave-instr/neighbor);
// dinv fused into scatter_ell; z table stored bf16 for decode.
//  0) memset: qcur = 0 (4 KB)
//  1) prep_wfrag: W1 -> bf16 MFMA A-fragment table (32 KB global)
//  2) bucket_edges: queues[d>>10] += (src,dst)   (1 read of edge list)
//  3) scatter_ell: per-1024-node slice, cnt in LDS atomics; writes cnt+dinv
//  4) gemm1_mfma: h1b = bf16((emb[x] @ W1) * dinv)   [N][128] bf16
//  5) agg1_ln: h2b = bf16(LN(relu(dinv*sum h1b + b1)))  (wave/node, 16B/lane)
//  6) gemm2: zsb = bf16((h2b @ W2) * dinv)
//  7) agg2: zb = bf16(dinv*(sum zsb) + b2)
//  8) decode: out = ((concat(zb[a],zb[b]) @ L1 + bl1) @ L2 + bl2)
// ---------------------------------------------------------------------------

typedef __attribute__((ext_vector_type(8))) __bf16 bf16x8;
typedef __attribute__((ext_vector_type(4))) __bf16 bf16x4;
typedef __attribute__((ext_vector_type(4))) float f32x4;

static __device__ __forceinline__ unsigned f2bf1(float x) {
  unsigned u = __float_as_uint(x);
  return (u + 0x7FFFu + ((u >> 16) & 1u)) >> 16;
}
static __device__ __forceinline__ unsigned packbf2(float lo, float hi) {
  return f2bf1(lo) | (f2bf1(hi) << 16);
}
static __device__ __forceinline__ float bfl(unsigned u) { return __uint_as_float(u << 16); }
static __device__ __forceinline__ float bfh(unsigned u) { return __uint_as_float(u & 0xFFFF0000u); }

// W1 fragment table: wfrag[((kt*8+ct)*64+lane)*8+j] = bf16(W1[kt*32+(lane>>4)*8+j][ct*16+(lane&15)])
__global__ __launch_bounds__(256) void prep_wfrag(const float* __restrict__ W1,
                                                  ushort* __restrict__ wfrag) {
  int idx = blockIdx.x * 256 + threadIdx.x;  // 64 blocks -> 16384 elements
  int j = idx & 7, lane = (idx >> 3) & 63, ct = (idx >> 9) & 7, kt = idx >> 12;
  int k = kt * 32 + (lane >> 4) * 8 + j;
  int col = ct * 16 + (lane & 15);
  __bf16 h = (__bf16)W1[k * 128 + col];
  wfrag[idx] = __builtin_bit_cast(ushort, h);
}

// Pass 1: read edges once, route to NB per-slice queues (slice = 1024 dsts).
__global__ __launch_bounds__(256) void bucket_edges(const int* __restrict__ src,
                                                    const int* __restrict__ dst,
                                                    int E, int NB,
                                                    int* __restrict__ qcur,
                                                    uint2* __restrict__ queues,
                                                    int qcap) {
  __shared__ int lcnt[128];
  __shared__ int lbase[128];
  int t = threadIdx.x;
  int CH = (E + gridDim.x - 1) / gridDim.x;
  int beg = blockIdx.x * CH;
  int end = min(E, beg + CH);
  for (int i = t; i < NB; i += 256) lcnt[i] = 0;
  __syncthreads();
  for (int e = beg + t; e < end; e += 256) atomicAdd(&lcnt[dst[e] >> 10], 1);
  __syncthreads();
  for (int i = t; i < NB; i += 256) {
    lbase[i] = atomicAdd(&qcur[i], lcnt[i]);
    lcnt[i] = 0;
  }
  __syncthreads();
  for (int e = beg + t; e < end; e += 256) {  // chunk is L2-hot now
    int d = dst[e];
    int p = d >> 10;
    int pos = lbase[p] + atomicAdd(&lcnt[p], 1);
    if (pos < qcap) queues[(size_t)p * qcap + pos] = make_uint2((unsigned)src[e], (unsigned)d);
  }
}

// Pass 2: one block per slice; cnt slice lives in LDS; also emits dinv.
__global__ __launch_bounds__(1024) void scatter_ell(const uint2* __restrict__ queues,
                                                    const int* __restrict__ qcur,
                                                    int qcap, int* __restrict__ cnt,
                                                    float* __restrict__ dinv,
                                                    int* __restrict__ colsrc, int N) {
  __shared__ int lcnt[1024];
  int b = blockIdx.x, t = threadIdx.x;
  lcnt[t] = 0;
  __syncthreads();
  int len = min(qcur[b], qcap);
  const uint2* q = queues + (size_t)b * qcap;
  int lo = b << 10;
  for (int i = t; i < len; i += 1024) {
    uint2 e = q[i];
    int pos = atomicAdd(&lcnt[e.y - lo], 1);
    if (pos < 64) colsrc[(size_t)e.y * 64 + pos] = (int)e.x;
  }
  __syncthreads();
  int node = lo + t;
  if (node < N) {
    int c = min(lcnt[t], 64);
    cnt[node] = c;
    dinv[node] = rsqrtf((float)(c + 1));
  }
}

// h1b[node][dim] bf16 = (emb[x[node]] @ W1) * dinv[node], via 16x16x32 MFMA.
__global__ __launch_bounds__(256) void gemm1_mfma(
    const int* __restrict__ x, const float* __restrict__ emb,
    const ushort* __restrict__ wfrag, const float* __restrict__ dinv,
    unsigned* __restrict__ h1b, int N) {
  __shared__ alignas(16) ushort Wlds[16384];  // 32 KB frag table
  int t = threadIdx.x;
  for (int i = t; i < 2048; i += 256)
    ((uint4*)Wlds)[i] = ((const uint4*)wfrag)[i];
  __syncthreads();
  int w = t >> 6, lane = t & 63;
  int row0 = blockIdx.x * 128 + w * 32;  // this wave: nodes row0..row0+31
  int rB = lane & 15, kg = lane >> 4;
  int n0 = row0 + rB, n1 = row0 + 16 + rB;
  const float* e0 = emb + (size_t)x[min(n0, N - 1)] * 128 + kg * 8;
  const float* e1 = emb + (size_t)x[min(n1, N - 1)] * 128 + kg * 8;
  f32x4 acc[2][8];
#pragma unroll
  for (int g = 0; g < 2; ++g)
#pragma unroll
    for (int ct = 0; ct < 8; ++ct) acc[g][ct] = (f32x4)(0.f);
#pragma unroll
  for (int kt = 0; kt < 4; ++kt) {
    float4 p0 = *(const float4*)(e0 + kt * 32);
    float4 p1 = *(const float4*)(e0 + kt * 32 + 4);
    float4 q0 = *(const float4*)(e1 + kt * 32);
    float4 q1 = *(const float4*)(e1 + kt * 32 + 4);
    bf16x8 fb0, fb1;
    fb0[0] = (__bf16)p0.x; fb0[1] = (__bf16)p0.y; fb0[2] = (__bf16)p0.z; fb0[3] = (__bf16)p0.w;
    fb0[4] = (__bf16)p1.x; fb0[5] = (__bf16)p1.y; fb0[6] = (__bf16)p1.z; fb0[7] = (__bf16)p1.w;
    fb1[0] = (__bf16)q0.x; fb1[1] = (__bf16)q0.y; fb1[2] = (__bf16)q0.z; fb1[3] = (__bf16)q0.w;
    fb1[4] = (__bf16)q1.x; fb1[5] = (__bf16)q1.y; fb1[6] = (__bf16)q1.z; fb1[7] = (__bf16)q1.w;
#pragma unroll
    for (int ct = 0; ct < 8; ++ct) {
      bf16x8 wv = *(const bf16x8*)&Wlds[((kt * 8 + ct) * 64 + lane) * 8];
      acc[0][ct] = __builtin_amdgcn_mfma_f32_16x16x32_bf16(wv, fb0, acc[0][ct], 0, 0, 0);
      acc[1][ct] = __builtin_amdgcn_mfma_f32_16x16x32_bf16(wv, fb1, acc[1][ct], 0, 0, 0);
    }
  }
#pragma unroll
  for (int g = 0; g < 2; ++g) {
    int node = row0 + g * 16 + rB;
    if (node < N) {
      float dv = dinv[node];
#pragma unroll
      for (int ct = 0; ct < 8; ++ct) {
        f32x4 a = acc[g][ct];
        bf16x4 o;
        o[0] = (__bf16)(a[0] * dv); o[1] = (__bf16)(a[1] * dv);
        o[2] = (__bf16)(a[2] * dv); o[3] = (__bf16)(a[3] * dv);
        *(uint2*)&h1b[(size_t)node * 64 + ct * 8 + kg * 2] = __builtin_bit_cast(uint2, o);
      }
    }
  }
}

// wave/node: lane=(g,dq); 16B/lane, 4 neighbors per step (8 in flight),
// cross-group reduce, then LN.  h2b = bf16(LN(relu(acc*dinv+b1)))
__global__ __launch_bounds__(256) void agg1_ln(const unsigned* __restrict__ h1b,
                                               const int* __restrict__ cnt_a,
                                               const int* __restrict__ colsrc,
                                               const float* __restrict__ dinv,
                                               const float* __restrict__ b1,
                                               const float* __restrict__ lng,
                                               const float* __restrict__ lnb,
                                               unsigned* __restrict__ h2b, int N) {
  int v = blockIdx.x * 4 + (threadIdx.x >> 6);
  int lane = threadIdx.x & 63;
  if (v >= N) return;
  int g = lane >> 4, dq = lane & 15;   // group g -> neighbor slot i+g; dims 8dq..8dq+7
  const uint4* tb = (const uint4*)h1b; // row = 16 x uint4
  int myidx = colsrc[(size_t)v * 64 + lane];
  int cnt = cnt_a[v];
  float a0 = 0.f, a1 = 0.f, a2 = 0.f, a3 = 0.f;
  float a4 = 0.f, a5 = 0.f, a6 = 0.f, a7 = 0.f;
#define ACC1(m)                                              \
  {                                                          \
    a0 += bfl(m.x); a1 += bfh(m.x); a2 += bfl(m.y);          \
    a3 += bfh(m.y); a4 += bfl(m.z); a5 += bfh(m.z);          \
    a6 += bfl(m.w); a7 += bfh(m.w);                          \
  }
  if (g == 0) {  // self loop (pre-scaled)
    uint4 ms = tb[(size_t)v * 16 + dq];
    ACC1(ms);
  }
  int i = 0;
  for (; i + 8 <= cnt; i += 8) {  // 8 rows in flight across the wave
    int s0 = __shfl(myidx, i + g, 64);
    int s1 = __shfl(myidx, i + 4 + g, 64);
    uint4 m0 = tb[(size_t)s0 * 16 + dq];
    uint4 m1 = tb[(size_t)s1 * 16 + dq];
    ACC1(m0);
    ACC1(m1);
  }
  for (; i < cnt; i += 4) {
    int slot = i + g;
    int s = __shfl(myidx, min(slot, cnt - 1), 64);  // uniform trip; shfl before guard
    uint4 m = tb[(size_t)s * 16 + dq];
    if (slot < cnt) ACC1(m);
  }
#undef ACC1
#pragma unroll
  for (int off = 16; off < 64; off <<= 1) {  // cross-group reduce
    a0 += __shfl_xor(a0, off, 64);
    a1 += __shfl_xor(a1, off, 64);
    a2 += __shfl_xor(a2, off, 64);
    a3 += __shfl_xor(a3, off, 64);
    a4 += __shfl_xor(a4, off, 64);
    a5 += __shfl_xor(a5, off, 64);
    a6 += __shfl_xor(a6, off, 64);
    a7 += __shfl_xor(a7, off, 64);
  }
  float dv = dinv[v];
  float4 bb0 = ((const float4*)b1)[dq * 2];
  float4 bb1 = ((const float4*)b1)[dq * 2 + 1];
  float v0 = fmaxf(a0 * dv + bb0.x, 0.f);
  float v1 = fmaxf(a1 * dv + bb0.y, 0.f);
  float v2 = fmaxf(a2 * dv + bb0.z, 0.f);
  float v3 = fmaxf(a3 * dv + bb0.w, 0.f);
  float v4 = fmaxf(a4 * dv + bb1.x, 0.f);
  float v5 = fmaxf(a5 * dv + bb1.y, 0.f);
  float v6 = fmaxf(a6 * dv + bb1.z, 0.f);
  float v7 = fmaxf(a7 * dv + bb1.w, 0.f);
  float s1 = ((v0 + v1) + (v2 + v3)) + ((v4 + v5) + (v6 + v7));
  float s2 = ((v0 * v0 + v1 * v1) + (v2 * v2 + v3 * v3)) +
             ((v4 * v4 + v5 * v5) + (v6 * v6 + v7 * v7));
#pragma unroll
  for (int off = 1; off < 16; off <<= 1) {  // LN reduce within 16-lane group
    s1 += __shfl_xor(s1, off, 64);
    s2 += __shfl_xor(s2, off, 64);
  }
  float mu = s1 * (1.f / 128.f);
  float var = s2 * (1.f / 128.f) - mu * mu;
  float rs = rsqrtf(var + 1e-5f);
  if (g == 0) {
    float4 gg0 = ((const float4*)lng)[dq * 2];
    float4 gg1 = ((const float4*)lng)[dq * 2 + 1];
    float4 nb0 = ((const float4*)lnb)[dq * 2];
    float4 nb1 = ((const float4*)lnb)[dq * 2 + 1];
    uint4 o;
    o.x = packbf2((v0 - mu) * rs * gg0.x + nb0.x, (v1 - mu) * rs * gg0.y + nb0.y);
    o.y = packbf2((v2 - mu) * rs * gg0.z + nb0.z, (v3 - mu) * rs * gg0.w + nb0.w);
    o.z = packbf2((v4 - mu) * rs * gg1.x + nb1.x, (v5 - mu) * rs * gg1.y + nb1.y);
    o.w = packbf2((v6 - mu) * rs * gg1.z + nb1.z, (v7 - mu) * rs * gg1.w + nb1.w);
    ((uint4*)h2b)[(size_t)v * 16 + dq] = o;
  }
}

// zsb[row][:] = bf16((h2b[row] @ W2) * dinv[row])   (128x16, bf16 input)
__global__ __launch_bounds__(256) void gemm2(const unsigned* __restrict__ h2b,
                                             const float* __restrict__ W2,
                                             const float* __restrict__ dinv,
                                             unsigned* __restrict__ zsb, int N) {
  __shared__ float W2s[128 * 16];  // 8 KB
  int t = threadIdx.x;
#pragma unroll
  for (int i = 0; i < 8; ++i) W2s[t + i * 256] = W2[t + i * 256];
  __syncthreads();
  int cp = t & 7, r = t >> 3;  // cp -> output dims 2cp,2cp+1; 32 rows/tile
  for (int rb = blockIdx.x * 32; rb < N; rb += gridDim.x * 32) {
    int row = rb + r;
    if (row >= N) continue;
    const uint4* xr = (const uint4*)(h2b + (size_t)row * 64);
    float a0 = 0.f, a1 = 0.f;
#pragma unroll
    for (int k8 = 0; k8 < 16; ++k8) {
      uint4 u = xr[k8];
      float f0 = bfl(u.x), f1 = bfh(u.x), f2 = bfl(u.y), f3 = bfh(u.y);
      float f4 = bfl(u.z), f5 = bfh(u.z), f6 = bfl(u.w), f7 = bfh(u.w);
      int kb = k8 * 8;
      float2 w;
      w = ((const float2*)W2s)[(kb + 0) * 8 + cp]; a0 += f0 * w.x; a1 += f0 * w.y;
      w = ((const float2*)W2s)[(kb + 1) * 8 + cp]; a0 += f1 * w.x; a1 += f1 * w.y;
      w = ((const float2*)W2s)[(kb + 2) * 8 + cp]; a0 += f2 * w.x; a1 += f2 * w.y;
      w = ((const float2*)W2s)[(kb + 3) * 8 + cp]; a0 += f3 * w.x; a1 += f3 * w.y;
      w = ((const float2*)W2s)[(kb + 4) * 8 + cp]; a0 += f4 * w.x; a1 += f4 * w.y;
      w = ((const float2*)W2s)[(kb + 5) * 8 + cp]; a0 += f5 * w.x; a1 += f5 * w.y;
      w = ((const float2*)W2s)[(kb + 6) * 8 + cp]; a0 += f6 * w.x; a1 += f6 * w.y;
      w = ((const float2*)W2s)[(kb + 7) * 8 + cp]; a0 += f7 * w.x; a1 += f7 * w.y;
    }
    float dv = dinv[row];
    zsb[(size_t)row * 8 + cp] = packbf2(a0 * dv, a1 * dv);
  }
}

// wave/node: lane=(g,q); 4 lanes x 8B per row, 16 neighbors in flight.
// Output z as bf16 (zb).
__global__ __launch_bounds__(256) void agg2(const unsigned* __restrict__ zsb,
                                            const int* __restrict__ cnt_a,
                                            const int* __restrict__ colsrc,
                                            const float* __restrict__ dinv,
                                            const float* __restrict__ b2,
                                            unsigned* __restrict__ zb, int N) {
  int v = blockIdx.x * 4 + (threadIdx.x >> 6);
  int lane = threadIdx.x & 63;
  if (v >= N) return;
  int g = lane >> 2, q = lane & 3;  // 16 neighbor groups, dims 4q..4q+3
  const uint2* tb = (const uint2*)zsb;  // row = 4 x uint2
  int myidx = colsrc[(size_t)v * 64 + lane];
  int cnt = cnt_a[v];
  float a0 = 0.f, a1 = 0.f, a2 = 0.f, a3 = 0.f;
  if (g == 0) {  // self loop
    uint2 m = tb[(size_t)v * 4 + q];
    a0 = bfl(m.x); a1 = bfh(m.x); a2 = bfl(m.y); a3 = bfh(m.y);
  }
  for (int i = 0; i < cnt; i += 16) {
    int slot = i + g;
    int s = __shfl(myidx, min(slot, cnt - 1), 64);
    uint2 m = tb[(size_t)s * 4 + q];
    if (slot < cnt) {
      a0 += bfl(m.x); a1 += bfh(m.x); a2 += bfl(m.y); a3 += bfh(m.y);
    }
  }
#pragma unroll
  for (int off = 4; off < 64; off <<= 1) {
    a0 += __shfl_xor(a0, off, 64);
    a1 += __shfl_xor(a1, off, 64);
    a2 += __shfl_xor(a2, off, 64);
    a3 += __shfl_xor(a3, off, 64);
  }
  if (g == 0) {
    float dv = dinv[v];
    float4 bb = ((const float4*)b2)[q];
    uint2 o;
    o.x = packbf2(a0 * dv + bb.x, a1 * dv + bb.y);
    o.y = packbf2(a2 * dv + bb.z, a3 * dv + bb.w);
    ((uint2*)zb)[(size_t)v * 4 + q] = o;
  }
}

__global__ __launch_bounds__(256) void decode(const int* __restrict__ eli,
                                              const unsigned* __restrict__ zb,
                                              const float* __restrict__ L1,
                                              const float* __restrict__ bl1,
                                              const float* __restrict__ L2,
                                              const float* __restrict__ bl2,
                                              float* __restrict__ out, int EL) {
  __shared__ float L1s[32 * 16];
  __shared__ float L2s[16];
  __shared__ float bl1s[16];
  __shared__ float bl2s;
  int t = threadIdx.x;
  L1s[t] = L1[t];
  L1s[256 + t] = L1[256 + t];
  if (t < 16) { L2s[t] = L2[t]; bl1s[t] = bl1[t]; }
  if (t == 0) bl2s = bl2[0];
  __syncthreads();
  int l = blockIdx.x * 256 + t;
  if (l >= EL) return;
  int a = eli[l], b = eli[EL + l];
  const uint4* zt = (const uint4*)zb;  // row = 2 x uint4
  uint4 ua0 = zt[(size_t)a * 2], ua1 = zt[(size_t)a * 2 + 1];
  uint4 ub0 = zt[(size_t)b * 2], ub1 = zt[(size_t)b * 2 + 1];
  float fa[16], fb[16];
  fa[0] = bfl(ua0.x); fa[1] = bfh(ua0.x); fa[2] = bfl(ua0.y); fa[3] = bfh(ua0.y);
  fa[4] = bfl(ua0.z); fa[5] = bfh(ua0.z); fa[6] = bfl(ua0.w); fa[7] = bfh(ua0.w);
  fa[8] = bfl(ua1.x); fa[9] = bfh(ua1.x); fa[10] = bfl(ua1.y); fa[11] = bfh(ua1.y);
  fa[12] = bfl(ua1.z); fa[13] = bfh(ua1.z); fa[14] = bfl(ua1.w); fa[15] = bfh(ua1.w);
  fb[0] = bfl(ub0.x); fb[1] = bfh(ub0.x); fb[2] = bfl(ub0.y); fb[3] = bfh(ub0.y);
  fb[4] = bfl(ub0.z); fb[5] = bfh(ub0.z); fb[6] = bfl(ub0.w); fb[7] = bfh(ub0.w);
  fb[8] = bfl(ub1.x); fb[9] = bfh(ub1.x); fb[10] = bfl(ub1.y); fb[11] = bfh(ub1.y);
  fb[12] = bfl(ub1.z); fb[13] = bfh(ub1.z); fb[14] = bfl(ub1.w); fb[15] = bfh(ub1.w);
  float h[16];
#pragma unroll
  for (int j = 0; j < 16; ++j) h[j] = bl1s[j];
#pragma unroll
  for (int k = 0; k < 16; ++k) {
#pragma unroll
    for (int j = 0; j < 16; ++j) {
      h[j] += fa[k] * L1s[k * 16 + j];
      h[j] += fb[k] * L1s[(16 + k) * 16 + j];
    }
  }
  float o = bl2s;
#pragma unroll
  for (int j = 0; j < 16; ++j) o += h[j] * L2s[j];
  out[l] = o;
}

extern "C" void kernel_launch(void* const* d_in, const int* in_sizes, int n_in,
                              void* d_out, int out_size, void* d_ws, size_t ws_size,
                              hipStream_t stream) {
  const int* x = (const int*)d_in[0];
  const int* ei = (const int*)d_in[1];
  const int* eli = (const int*)d_in[2];
  const float* emb = (const float*)d_in[3];
  const float* W1 = (const float*)d_in[4];
  const float* b1 = (const float*)d_in[5];
  const float* lng = (const float*)d_in[6];
  const float* lnb = (const float*)d_in[7];
  const float* W2 = (const float*)d_in[8];
  const float* b2 = (const float*)d_in[9];
  const float* L1 = (const float*)d_in[10];
  const float* bl1 = (const float*)d_in[11];
  const float* L2 = (const float*)d_in[12];
  const float* bl2 = (const float*)d_in[13];

  int N = in_sizes[0];
  int E = in_sizes[1] / 2;
  int EL = in_sizes[2] / 2;
  const int* src = ei;
  const int* dst = ei + E;

  int NB = (N + 1023) >> 10;            // 1024-node dst slices
  int qcap = E / NB + 4096;             // Poisson slack

  char* ws = (char*)d_ws;
  auto align256 = [](size_t v) { return (v + 255) & ~(size_t)255; };
  size_t p = 0;
  int* qcur = (int*)(ws + p); p += 4096;  // zeroed (covers NB <= 1024)
  int* cnt = (int*)(ws + p); p += align256((size_t)N * 4);
  float* dinv = (float*)(ws + p); p += align256((size_t)N * 4);
  ushort* wfrag = (ushort*)(ws + p); p += align256(16384 * 2);
  int* colsrc = (int*)(ws + p); p += align256((size_t)N * 64 * 4);
  uint2* queues = (uint2*)(ws + p); p += align256((size_t)NB * qcap * 8);
  unsigned* h1b = (unsigned*)(ws + p); p += align256((size_t)N * 64 * 4);
  unsigned* h2b = (unsigned*)(ws + p); p += align256((size_t)N * 64 * 4);
  unsigned* zsb = (unsigned*)(ws + p); p += align256((size_t)N * 8 * 4);
  unsigned* zb = (unsigned*)(ws + p); p += align256((size_t)N * 8 * 4);
  (void)ws_size; (void)n_in; (void)out_size;

  hipMemsetAsync(qcur, 0, 4096, stream);

  prep_wfrag<<<64, 256, 0, stream>>>(W1, wfrag);
  bucket_edges<<<512, 256, 0, stream>>>(src, dst, E, NB, qcur, queues, qcap);
  scatter_ell<<<NB, 1024, 0, stream>>>(queues, qcur, qcap, cnt, dinv, colsrc, N);
  gemm1_mfma<<<(N + 127) / 128, 256, 0, stream>>>(x, emb, wfrag, dinv, h1b, N);
  agg1_ln<<<(N + 3) / 4, 256, 0, stream>>>(h1b, cnt, colsrc, dinv, b1, lng, lnb, h2b, N);
  gemm2<<<512, 256, 0, stream>>>(h2b, W2, dinv, zsb, N);
  agg2<<<(N + 3) / 4, 256, 0, stream>>>(zsb, cnt, colsrc, dinv, b2, zb, N);
  decode<<<(EL + 255) / 256, 256, 0, stream>>>(eli, zb, L1, bl1, L2, bl2,
                                               (float*)d_out, EL);
}